// Round 1
// baseline (1959.272 us; speedup 1.0000x reference)
//
#include <hip/hip_runtime.h>
#include <hip/hip_bf16.h>

#define NN 100000
#define NE 1600000
#define DH 128

// ---------------- workspace layout (byte offsets) ----------------
// cnt     @ 0        : NN int   (in-degree)
// offsets @ 512KB    : NN int   (CSR row starts)
// cursor  @ 1MB      : NN int   (fill cursors)
// tail    @ 1.5MB    : int      (range allocator)
// flag    @ 1.5MB+64 : int      (edge dtype: 1 = int64, 0 = int32)
// csr     @ 2MB      : NE int   (src indices grouped by dst) -> ends 8.4MB
// Wt1     @ 8.5MB    : 256*128 float (transposed concat [Wl1;Wr1])
// Wt2     @ 8.75MB   : 256*128 float
// agg     @ 9MB      : NN*128 float (51.2MB) -> total ~60.2MB
#define OFF_CNT    (0)
#define OFF_OFFS   (512u << 10)
#define OFF_CUR    (1u << 20)
#define OFF_TAIL   (1536u << 10)
#define OFF_CSR    (2u << 20)
#define OFF_WT1    (8704u << 10)
#define OFF_WT2    (8960u << 10)
#define OFF_AGG    (9u << 20)

// Detect whether edge_index is stored as int64 or int32.
// int64 values are all < NN; int32 read as int64 pairs two indices -> huge.
__global__ void detect_kernel(const void* edges, int* flag) {
    if (threadIdx.x == 0 && blockIdx.x == 0) {
        const long long* e = (const long long*)edges;
        int ok = 1;
        for (int i = 0; i < 4; i++) {
            long long v = e[i];
            if (v < 0 || v >= NN) ok = 0;
        }
        *flag = ok;
    }
}

__global__ void count_kernel(const void* edges, const int* flag, int* cnt) {
    int i = blockIdx.x * blockDim.x + threadIdx.x;
    if (i >= NE) return;
    int f = *flag;
    int d = f ? (int)((const long long*)edges)[NE + i]
              : ((const int*)edges)[NE + i];
    atomicAdd(&cnt[d], 1);
}

__global__ void alloc_kernel(const int* cnt, int* offsets, int* tail) {
    int n = blockIdx.x * blockDim.x + threadIdx.x;
    if (n >= NN) return;
    offsets[n] = atomicAdd(tail, cnt[n]);
}

__global__ void fill_kernel(const void* edges, const int* flag,
                            const int* offsets, int* cursor, int* csr) {
    int i = blockIdx.x * blockDim.x + threadIdx.x;
    if (i >= NE) return;
    int f = *flag;
    int s, d;
    if (f) {
        const long long* e = (const long long*)edges;
        s = (int)e[i];
        d = (int)e[NE + i];
    } else {
        const int* e = (const int*)edges;
        s = e[i];
        d = e[NE + i];
    }
    int pos = atomicAdd(&cursor[d], 1);
    csr[offsets[d] + pos] = s;
}

// Wt[k*128+o] = (k<128) ? Wl[o][k] : Wr[o][k-128]  (transposed, concatenated K=256)
__global__ void wtprep_kernel(const float* Wl, const float* Wr, float* Wt) {
    int i = blockIdx.x * blockDim.x + threadIdx.x;
    if (i >= 256 * 128) return;
    int k = i >> 7, o = i & 127;
    Wt[i] = (k < 128) ? Wl[o * 128 + k] : Wr[o * 128 + (k - 128)];
}

// One wave per node; each lane owns a float2 slice of the 128-float row.
__global__ __launch_bounds__(256) void agg_kernel(const float* feat, const int* csr,
                                                  const int* offsets, const int* cnt,
                                                  float* agg) {
    int node = blockIdx.x * 4 + (threadIdx.x >> 6);
    int lane = threadIdx.x & 63;
    if (node >= NN) return;
    int beg = offsets[node];
    int deg = cnt[node];
    float ax = 0.f, ay = 0.f;
    int j = 0;
    for (; j + 4 <= deg; j += 4) {
        int s0 = csr[beg + j + 0];
        int s1 = csr[beg + j + 1];
        int s2 = csr[beg + j + 2];
        int s3 = csr[beg + j + 3];
        float2 v0 = ((const float2*)(feat + (size_t)s0 * DH))[lane];
        float2 v1 = ((const float2*)(feat + (size_t)s1 * DH))[lane];
        float2 v2 = ((const float2*)(feat + (size_t)s2 * DH))[lane];
        float2 v3 = ((const float2*)(feat + (size_t)s3 * DH))[lane];
        ax += v0.x + v1.x + v2.x + v3.x;
        ay += v0.y + v1.y + v2.y + v3.y;
    }
    for (; j < deg; j++) {
        int s = csr[beg + j];
        float2 v = ((const float2*)(feat + (size_t)s * DH))[lane];
        ax += v.x;
        ay += v.y;
    }
    float inv = (deg > 0) ? 1.0f / (float)deg : 0.0f;  // deg==0 -> agg row is 0 anyway
    ((float2*)(agg + (size_t)node * DH))[lane] = make_float2(ax * inv, ay * inv);
}

// out[n,o] = sum_k A[n,k]*Wt[k][o] (k<128 part) + B[n,k-128]*Wt[k][o] (k>=128) + bias[o]
// 32 nodes per block, 256 threads: thread = (node 0..31) x (16-output group).
// Safe when B == out: each block stages its own 32 rows into LDS before writing.
__global__ __launch_bounds__(256) void linear_kernel(const float* A, const float* B,
                                                     const float* Wt, const float* bias,
                                                     float* out, int relu) {
    __shared__ __align__(16) float In[32][260];  // stride 260: node-groups hit distinct banks
    int tid = threadIdx.x;
    int nb = blockIdx.x * 32;

    // stage: 32 rows x 256 floats (A row ++ B row), float4 per element group
    for (int i = tid; i < 32 * 64; i += 256) {
        int node = i >> 6;
        int c4 = i & 63;
        float4 v;
        if (c4 < 32)
            v = ((const float4*)(A + (size_t)(nb + node) * 128))[c4];
        else
            v = ((const float4*)(B + (size_t)(nb + node) * 128))[c4 - 32];
        *(float4*)(&In[node][c4 * 4]) = v;
    }
    __syncthreads();

    int node = tid >> 3;
    int og = (tid & 7) * 16;
    float acc[16];
#pragma unroll
    for (int q = 0; q < 16; q++) acc[q] = 0.f;

#pragma unroll 4
    for (int k = 0; k < 256; k++) {
        float a = In[node][k];
        const float4* wp = (const float4*)(Wt + k * 128 + og);
#pragma unroll
        for (int q = 0; q < 4; q++) {
            float4 wv = wp[q];
            acc[4 * q + 0] += a * wv.x;
            acc[4 * q + 1] += a * wv.y;
            acc[4 * q + 2] += a * wv.z;
            acc[4 * q + 3] += a * wv.w;
        }
    }

    float* op = out + (size_t)(nb + node) * 128 + og;
#pragma unroll
    for (int q = 0; q < 16; q++) {
        float r = acc[q] + bias[og + q];
        if (relu) r = fmaxf(r, 0.f);
        op[q] = r;
    }
}

extern "C" void kernel_launch(void* const* d_in, const int* in_sizes, int n_in,
                              void* d_out, int out_size, void* d_ws, size_t ws_size,
                              hipStream_t stream) {
    const float* x   = (const float*)d_in[0];
    const void* edges = d_in[1];
    const float* Wl1 = (const float*)d_in[2];
    const float* Wr1 = (const float*)d_in[3];
    const float* b1  = (const float*)d_in[4];
    const float* Wl2 = (const float*)d_in[5];
    const float* Wr2 = (const float*)d_in[6];
    const float* b2  = (const float*)d_in[7];
    float* out = (float*)d_out;

    char* ws = (char*)d_ws;
    int* cnt     = (int*)(ws + OFF_CNT);
    int* offsets = (int*)(ws + OFF_OFFS);
    int* cursor  = (int*)(ws + OFF_CUR);
    int* tail    = (int*)(ws + OFF_TAIL);
    int* flag    = (int*)(ws + OFF_TAIL + 64);
    int* csr     = (int*)(ws + OFF_CSR);
    float* Wt1   = (float*)(ws + OFF_WT1);
    float* Wt2   = (float*)(ws + OFF_WT2);
    float* agg   = (float*)(ws + OFF_AGG);

    hipMemsetAsync(cnt, 0, NN * sizeof(int), stream);
    hipMemsetAsync(cursor, 0, NN * sizeof(int), stream);
    hipMemsetAsync(tail, 0, 2 * 64, stream);

    detect_kernel<<<1, 1, 0, stream>>>(edges, flag);
    count_kernel<<<(NE + 255) / 256, 256, 0, stream>>>(edges, flag, cnt);
    alloc_kernel<<<(NN + 255) / 256, 256, 0, stream>>>(cnt, offsets, tail);
    fill_kernel<<<(NE + 255) / 256, 256, 0, stream>>>(edges, flag, offsets, cursor, csr);

    wtprep_kernel<<<(256 * 128 + 255) / 256, 256, 0, stream>>>(Wl1, Wr1, Wt1);
    wtprep_kernel<<<(256 * 128 + 255) / 256, 256, 0, stream>>>(Wl2, Wr2, Wt2);

    // layer 1: agg1 = mean-gather(x); h = relu(lin(agg1, x)) -> written to d_out
    agg_kernel<<<NN / 4, 256, 0, stream>>>(x, csr, offsets, cnt, agg);
    linear_kernel<<<NN / 32, 256, 0, stream>>>(agg, x, Wt1, b1, out, 1);

    // layer 2: agg2 = mean-gather(h); out = lin(agg2, h)  (in-place on d_out)
    agg_kernel<<<NN / 4, 256, 0, stream>>>(out, csr, offsets, cnt, agg);
    linear_kernel<<<NN / 32, 256, 0, stream>>>(agg, out, Wt2, b2, out, 0);
}

// Round 2
// 663.448 us; speedup vs baseline: 2.9532x; 2.9532x over previous
//
#include <hip/hip_runtime.h>
#include <hip/hip_bf16.h>

#define NN 100000
#define NE 1600000
#define DH 128

// ---------------- workspace layout (byte offsets) ----------------
#define OFF_CNT    (0)
#define OFF_OFFS   (512u << 10)
#define OFF_CUR    (1u << 20)
#define OFF_TAIL   (1536u << 10)
#define OFF_CSR    (2u << 20)
#define OFF_WT1    (8704u << 10)
#define OFF_WT2    (8960u << 10)
#define OFF_AGG    (9u << 20)

__global__ void detect_kernel(const void* edges, int* flag) {
    if (threadIdx.x == 0 && blockIdx.x == 0) {
        const long long* e = (const long long*)edges;
        int ok = 1;
        for (int i = 0; i < 4; i++) {
            long long v = e[i];
            if (v < 0 || v >= NN) ok = 0;
        }
        *flag = ok;
    }
}

__global__ void count_kernel(const void* edges, const int* flag, int* cnt) {
    int i = blockIdx.x * blockDim.x + threadIdx.x;
    if (i >= NE) return;
    int f = *flag;
    int d = f ? (int)((const long long*)edges)[NE + i]
              : ((const int*)edges)[NE + i];
    atomicAdd(&cnt[d], 1);
}

__global__ void alloc_kernel(const int* cnt, int* offsets, int* tail) {
    int n = blockIdx.x * blockDim.x + threadIdx.x;
    if (n >= NN) return;
    offsets[n] = atomicAdd(tail, cnt[n]);
}

__global__ void fill_kernel(const void* edges, const int* flag,
                            const int* offsets, int* cursor, int* csr) {
    int i = blockIdx.x * blockDim.x + threadIdx.x;
    if (i >= NE) return;
    int f = *flag;
    int s, d;
    if (f) {
        const long long* e = (const long long*)edges;
        s = (int)e[i];
        d = (int)e[NE + i];
    } else {
        const int* e = (const int*)edges;
        s = e[i];
        d = e[NE + i];
    }
    int pos = atomicAdd(&cursor[d], 1);
    csr[offsets[d] + pos] = s;
}

// Wt[k*128+o] = (k<128) ? Wl[o][k] : Wr[o][k-128]  (transposed, concatenated K=256)
__global__ void wtprep_kernel(const float* Wl, const float* Wr, float* Wt) {
    int i = blockIdx.x * blockDim.x + threadIdx.x;
    if (i >= 256 * 128) return;
    int k = i >> 7, o = i & 127;
    Wt[i] = (k < 128) ? Wl[o * 128 + k] : Wr[o * 128 + (k - 128)];
}

// One wave per node; each lane owns a float2 slice of the 128-float row.
__global__ __launch_bounds__(256) void agg_kernel(const float* feat, const int* csr,
                                                  const int* offsets, const int* cnt,
                                                  float* agg) {
    int node = blockIdx.x * 4 + (threadIdx.x >> 6);
    int lane = threadIdx.x & 63;
    if (node >= NN) return;
    int beg = offsets[node];
    int deg = cnt[node];
    float ax = 0.f, ay = 0.f;
    int j = 0;
    for (; j + 4 <= deg; j += 4) {
        int s0 = csr[beg + j + 0];
        int s1 = csr[beg + j + 1];
        int s2 = csr[beg + j + 2];
        int s3 = csr[beg + j + 3];
        float2 v0 = ((const float2*)(feat + (size_t)s0 * DH))[lane];
        float2 v1 = ((const float2*)(feat + (size_t)s1 * DH))[lane];
        float2 v2 = ((const float2*)(feat + (size_t)s2 * DH))[lane];
        float2 v3 = ((const float2*)(feat + (size_t)s3 * DH))[lane];
        ax += v0.x + v1.x + v2.x + v3.x;
        ay += v0.y + v1.y + v2.y + v3.y;
    }
    for (; j < deg; j++) {
        int s = csr[beg + j];
        float2 v = ((const float2*)(feat + (size_t)s * DH))[lane];
        ax += v.x;
        ay += v.y;
    }
    float inv = (deg > 0) ? 1.0f / (float)deg : 0.0f;
    ((float2*)(agg + (size_t)node * DH))[lane] = make_float2(ax * inv, ay * inv);
}

// Register-tiled f32 GEMM: out[n,o] = sum_{k<128} A[n,k]*Wt[k][o]
//                                   + sum_{k>=128} B[n,k-128]*Wt[k][o] + bias[o]
// Block tile: 128 nodes x 128 outputs, K chunked by 64 (chunks 0,1 from A; 2,3 from B).
// Thread (256/block): ng = tid>>4 (8 nodes), og = tid&15 (8 outputs) -> 8x8 register tile.
// LDS: In_s[128][64] (XOR-swizzled float4 index to kill 4-way node-group conflicts),
//      Wt_s[64][128]. 64KB total -> 2 blocks/CU.
// In-place safe for B==out: a block only reads its OWN 128 rows of B, and all its
// staging happens before its stores.
__global__ __launch_bounds__(256) void linear_kernel(const float* A, const float* B,
                                                     const float* Wt, const float* bias,
                                                     float* out, int relu) {
    __shared__ __align__(16) float In_s[128][64];
    __shared__ __align__(16) float Wt_s[64][128];

    int tid = threadIdx.x;
    int nb = blockIdx.x * 128;
    int ng = tid >> 4;       // node group: rows ng*8 .. ng*8+7
    int og = tid & 15;       // output group: cols og*8 .. og*8+7

    float acc[8][8];
#pragma unroll
    for (int i = 0; i < 8; i++)
#pragma unroll
        for (int q = 0; q < 8; q++) acc[i][q] = 0.f;

    for (int chunk = 0; chunk < 4; chunk++) {
        const float* Base = (chunk < 2) ? A : B;
        int kcol = (chunk & 1) * 64;   // column offset within the 128-wide operand
        int k0 = chunk * 64;           // row offset within Wt

        __syncthreads();  // protect LDS reuse from previous chunk's compute

        // stage In_s: 128 rows x 16 float4, swizzled f4 index = c ^ (row>>3 & 3)
        for (int idx = tid; idx < 128 * 16; idx += 256) {
            int row = idx >> 4;
            int c = idx & 15;
            float4 v = make_float4(0.f, 0.f, 0.f, 0.f);
            if (nb + row < NN)
                v = *(const float4*)(Base + (size_t)(nb + row) * 128 + kcol + c * 4);
            int sc = c ^ ((row >> 3) & 3);
            *(float4*)&In_s[row][sc * 4] = v;
        }
        // stage Wt_s: 64 rows x 32 float4
        for (int idx = tid; idx < 64 * 32; idx += 256) {
            int r = idx >> 5;
            int c = idx & 31;
            *(float4*)&Wt_s[r][c * 4] = *(const float4*)(Wt + (size_t)(k0 + r) * 128 + c * 4);
        }
        __syncthreads();

#pragma unroll 2
        for (int kk = 0; kk < 64; kk += 4) {
            float4 wv[4][2];
#pragma unroll
            for (int d = 0; d < 4; d++) {
                wv[d][0] = *(const float4*)&Wt_s[kk + d][og * 8];
                wv[d][1] = *(const float4*)&Wt_s[kk + d][og * 8 + 4];
            }
            int k4 = kk >> 2;
#pragma unroll
            for (int i = 0; i < 8; i++) {
                int row = ng * 8 + i;
                int sc = k4 ^ ((row >> 3) & 3);
                float4 a = *(const float4*)&In_s[row][sc * 4];
#pragma unroll
                for (int d = 0; d < 4; d++) {
                    float av = (d == 0) ? a.x : (d == 1) ? a.y : (d == 2) ? a.z : a.w;
                    acc[i][0] += av * wv[d][0].x;
                    acc[i][1] += av * wv[d][0].y;
                    acc[i][2] += av * wv[d][0].z;
                    acc[i][3] += av * wv[d][0].w;
                    acc[i][4] += av * wv[d][1].x;
                    acc[i][5] += av * wv[d][1].y;
                    acc[i][6] += av * wv[d][1].z;
                    acc[i][7] += av * wv[d][1].w;
                }
            }
        }
    }

    float4 bv0 = *(const float4*)(bias + og * 8);
    float4 bv1 = *(const float4*)(bias + og * 8 + 4);
#pragma unroll
    for (int i = 0; i < 8; i++) {
        int node = nb + ng * 8 + i;
        if (node >= NN) continue;
        float r0 = acc[i][0] + bv0.x, r1 = acc[i][1] + bv0.y;
        float r2 = acc[i][2] + bv0.z, r3 = acc[i][3] + bv0.w;
        float r4 = acc[i][4] + bv1.x, r5 = acc[i][5] + bv1.y;
        float r6 = acc[i][6] + bv1.z, r7 = acc[i][7] + bv1.w;
        if (relu) {
            r0 = fmaxf(r0, 0.f); r1 = fmaxf(r1, 0.f); r2 = fmaxf(r2, 0.f); r3 = fmaxf(r3, 0.f);
            r4 = fmaxf(r4, 0.f); r5 = fmaxf(r5, 0.f); r6 = fmaxf(r6, 0.f); r7 = fmaxf(r7, 0.f);
        }
        float* op = out + (size_t)node * 128 + og * 8;
        *(float4*)op = make_float4(r0, r1, r2, r3);
        *(float4*)(op + 4) = make_float4(r4, r5, r6, r7);
    }
}

extern "C" void kernel_launch(void* const* d_in, const int* in_sizes, int n_in,
                              void* d_out, int out_size, void* d_ws, size_t ws_size,
                              hipStream_t stream) {
    const float* x   = (const float*)d_in[0];
    const void* edges = d_in[1];
    const float* Wl1 = (const float*)d_in[2];
    const float* Wr1 = (const float*)d_in[3];
    const float* b1  = (const float*)d_in[4];
    const float* Wl2 = (const float*)d_in[5];
    const float* Wr2 = (const float*)d_in[6];
    const float* b2  = (const float*)d_in[7];
    float* out = (float*)d_out;

    char* ws = (char*)d_ws;
    int* cnt     = (int*)(ws + OFF_CNT);
    int* offsets = (int*)(ws + OFF_OFFS);
    int* cursor  = (int*)(ws + OFF_CUR);
    int* tail    = (int*)(ws + OFF_TAIL);
    int* flag    = (int*)(ws + OFF_TAIL + 64);
    int* csr     = (int*)(ws + OFF_CSR);
    float* Wt1   = (float*)(ws + OFF_WT1);
    float* Wt2   = (float*)(ws + OFF_WT2);
    float* agg   = (float*)(ws + OFF_AGG);

    hipMemsetAsync(cnt, 0, NN * sizeof(int), stream);
    hipMemsetAsync(cursor, 0, NN * sizeof(int), stream);
    hipMemsetAsync(tail, 0, 2 * 64, stream);

    detect_kernel<<<1, 1, 0, stream>>>(edges, flag);
    count_kernel<<<(NE + 255) / 256, 256, 0, stream>>>(edges, flag, cnt);
    alloc_kernel<<<(NN + 255) / 256, 256, 0, stream>>>(cnt, offsets, tail);
    fill_kernel<<<(NE + 255) / 256, 256, 0, stream>>>(edges, flag, offsets, cursor, csr);

    wtprep_kernel<<<(256 * 128 + 255) / 256, 256, 0, stream>>>(Wl1, Wr1, Wt1);
    wtprep_kernel<<<(256 * 128 + 255) / 256, 256, 0, stream>>>(Wl2, Wr2, Wt2);

    int lgrid = (NN + 127) / 128;

    // layer 1: agg1 = mean-gather(x); h = relu(lin(agg1, x)) -> d_out
    agg_kernel<<<NN / 4, 256, 0, stream>>>(x, csr, offsets, cnt, agg);
    linear_kernel<<<lgrid, 256, 0, stream>>>(agg, x, Wt1, b1, out, 1);

    // layer 2: agg2 = mean-gather(h); out = lin(agg2, h)  (in-place on d_out)
    agg_kernel<<<NN / 4, 256, 0, stream>>>(out, csr, offsets, cnt, agg);
    linear_kernel<<<lgrid, 256, 0, stream>>>(agg, out, Wt2, b2, out, 0);
}

// Round 3
// 435.365 us; speedup vs baseline: 4.5003x; 1.5239x over previous
//
#include <hip/hip_runtime.h>
#include <hip/hip_bf16.h>

#define NN 100000
#define NE 1600000

typedef unsigned short u16;
typedef unsigned int u32;
using frag  = __attribute__((ext_vector_type(8))) short;   // 8 bf16 = 4 VGPR
using f32x4 = __attribute__((ext_vector_type(4))) float;   // MFMA C/D

// ---------------- workspace layout (byte offsets) ----------------
// cnt 400KB | offsets 400KB | cursor 400KB | tail/flag | csr 6.4MB
// Wst1/Wst2 64KB each (bf16, [kb][col][8] packed) | xb 25.6MB | aggb 25.6MB
#define OFF_CNT   (0)
#define OFF_OFFS  (512u << 10)
#define OFF_CUR   (1u << 20)
#define OFF_TAIL  (1536u << 10)
#define OFF_CSR   (2u << 20)
#define OFF_WT1   (8704u << 10)
#define OFF_WT2   ((8704u << 10) + 65536u)
#define OFF_XB    (9u << 20)
#define OFF_AGGB  (35037184u)   // OFF_XB + 25,600,000

// round-to-nearest-even f32 -> bf16 bits (explicit, no API ambiguity)
__device__ __forceinline__ u16 f2bf(float f) {
    u32 u = __float_as_uint(f);
    u32 r = u + 0x7fffu + ((u >> 16) & 1u);
    return (u16)(r >> 16);
}

__global__ void detect_kernel(const void* edges, int* flag) {
    if (threadIdx.x == 0 && blockIdx.x == 0) {
        const long long* e = (const long long*)edges;
        int ok = 1;
        for (int i = 0; i < 4; i++) {
            long long v = e[i];
            if (v < 0 || v >= NN) ok = 0;
        }
        *flag = ok;
    }
}

__global__ void count_kernel(const void* edges, const int* flag, int* cnt) {
    int i = blockIdx.x * blockDim.x + threadIdx.x;
    if (i >= NE) return;
    int f = *flag;
    int d = f ? (int)((const long long*)edges)[NE + i]
              : ((const int*)edges)[NE + i];
    atomicAdd(&cnt[d], 1);
}

__global__ void alloc_kernel(const int* cnt, int* offsets, int* tail) {
    int n = blockIdx.x * blockDim.x + threadIdx.x;
    if (n >= NN) return;
    offsets[n] = atomicAdd(tail, cnt[n]);
}

__global__ void fill_kernel(const void* edges, const int* flag,
                            const int* offsets, int* cursor, int* csr) {
    int i = blockIdx.x * blockDim.x + threadIdx.x;
    if (i >= NE) return;
    int f = *flag;
    int s, d;
    if (f) {
        const long long* e = (const long long*)edges;
        s = (int)e[i];
        d = (int)e[NE + i];
    } else {
        const int* e = (const int*)edges;
        s = e[i];
        d = e[NE + i];
    }
    int pos = atomicAdd(&cursor[d], 1);
    csr[offsets[d] + pos] = s;
}

// Wst[kb*1024 + col*8 + i] = bf16( k<128 ? Wl[col][k] : Wr[col][k-128] ), k = kb*8+i
// (kb in [0,32), col in [0,128), i in [0,8)) -> B-fragments are contiguous 16B reads.
__global__ void wtprep_kernel(const float* Wl, const float* Wr, u16* Wst) {
    int idx = blockIdx.x * 256 + threadIdx.x;
    if (idx >= 32 * 128 * 8) return;
    int kb = idx >> 10, col = (idx >> 3) & 127, i = idx & 7;
    int k = kb * 8 + i;
    float v = (k < 128) ? Wl[col * 128 + k] : Wr[col * 128 + (k - 128)];
    Wst[idx] = f2bf(v);
}

// f32 x -> bf16 xb, 8 elems/thread
__global__ void cvt_kernel(const float* x, u16* xb) {
    size_t base = ((size_t)blockIdx.x * 256 + threadIdx.x) * 8;
    if (base >= (size_t)NN * 128) return;
    float4 v0 = *(const float4*)(x + base);
    float4 v1 = *(const float4*)(x + base + 4);
    uint4 w;
    w.x = (u32)f2bf(v0.x) | ((u32)f2bf(v0.y) << 16);
    w.y = (u32)f2bf(v0.z) | ((u32)f2bf(v0.w) << 16);
    w.z = (u32)f2bf(v1.x) | ((u32)f2bf(v1.y) << 16);
    w.w = (u32)f2bf(v1.z) | ((u32)f2bf(v1.w) << 16);
    *(uint4*)(xb + base) = w;
}

// One wave per node; lane owns 2 bf16 elems (4B) of the 128-wide row. f32 accumulate.
__global__ __launch_bounds__(256) void agg_kernel(const u16* feat, const int* csr,
                                                  const int* offsets, const int* cnt,
                                                  u16* aggb) {
    int node = blockIdx.x * 4 + (threadIdx.x >> 6);
    int lane = threadIdx.x & 63;
    if (node >= NN) return;
    int beg = offsets[node];
    int deg = cnt[node];
    float ax = 0.f, ay = 0.f;
    int j = 0;
    for (; j + 4 <= deg; j += 4) {
        int s0 = csr[beg + j + 0];
        int s1 = csr[beg + j + 1];
        int s2 = csr[beg + j + 2];
        int s3 = csr[beg + j + 3];
        u32 u0 = *(const u32*)(feat + (size_t)s0 * 128 + lane * 2);
        u32 u1 = *(const u32*)(feat + (size_t)s1 * 128 + lane * 2);
        u32 u2 = *(const u32*)(feat + (size_t)s2 * 128 + lane * 2);
        u32 u3 = *(const u32*)(feat + (size_t)s3 * 128 + lane * 2);
        ax += __uint_as_float(u0 << 16) + __uint_as_float(u1 << 16)
            + __uint_as_float(u2 << 16) + __uint_as_float(u3 << 16);
        ay += __uint_as_float(u0 & 0xffff0000u) + __uint_as_float(u1 & 0xffff0000u)
            + __uint_as_float(u2 & 0xffff0000u) + __uint_as_float(u3 & 0xffff0000u);
    }
    for (; j < deg; j++) {
        int s = csr[beg + j];
        u32 u = *(const u32*)(feat + (size_t)s * 128 + lane * 2);
        ax += __uint_as_float(u << 16);
        ay += __uint_as_float(u & 0xffff0000u);
    }
    float inv = (deg > 0) ? 1.0f / (float)deg : 0.0f;
    u32 packed = (u32)f2bf(ax * inv) | ((u32)f2bf(ay * inv) << 16);
    *(u32*)(aggb + (size_t)node * 128 + lane * 2) = packed;
}

// MFMA GEMM: out[n,o] = sum_k [A||B][n,k] * W[k,o] + bias[o], K=256 (chunk0=A, chunk1=B).
// Block: 128 nodes x 128 outs, 4 waves (2x2), wave = 4x4 frags of 16x16x32.
// A/B frags share the same (lane,elem)->k map, so HW k-permutation cancels.
// In-place safe when outH aliases Bbuf: block stages its own 128 B-rows (chunk 1)
// before any store, and no other block touches those rows.
__global__ __launch_bounds__(256) void lin_kernel(const u16* __restrict__ Abuf,
                                                  const u16* __restrict__ Bbuf,
                                                  const u16* __restrict__ Wst,
                                                  const float* __restrict__ bias,
                                                  float* outF, u16* outH, int relu) {
    __shared__ u16 As[128][136];   // +8 pad: row stride 272B -> rows 4 banks apart
    __shared__ u16 Ws[16384];      // [16 kb][128 col][8 k] bf16, chunk-local

    int tid = threadIdx.x;
    int lane = tid & 63;
    int wid = tid >> 6;
    int wr = wid >> 1, wc = wid & 1;
    int nb = blockIdx.x * 128;
    int l15 = lane & 15, l4 = lane >> 4;

    f32x4 acc[4][4];
#pragma unroll
    for (int i = 0; i < 4; i++)
#pragma unroll
        for (int j = 0; j < 4; j++) acc[i][j] = (f32x4){0.f, 0.f, 0.f, 0.f};

    for (int c = 0; c < 2; c++) {
        const u16* Base = c ? Bbuf : Abuf;
        __syncthreads();  // protect previous chunk's LDS from overwrite

        // stage A-tile: 128 rows x 128 bf16 (2048 x 16B), reg-staged
#pragma unroll
        for (int it = 0; it < 8; it++) {
            int idx = it * 256 + tid;
            int row = idx >> 4, c16 = idx & 15;
            float4 v = make_float4(0.f, 0.f, 0.f, 0.f);
            if (nb + row < NN)
                v = *(const float4*)(Base + (size_t)(nb + row) * 128 + c16 * 8);
            *(float4*)&As[row][c16 * 8] = v;
        }
        // stage W chunk: linear 32KB copy
        const u16* wsrc = Wst + c * 16384;
#pragma unroll
        for (int it = 0; it < 8; it++) {
            int idx = it * 256 + tid;
            *(float4*)&Ws[idx * 8] = *(const float4*)(wsrc + idx * 8);
        }
        __syncthreads();

#pragma unroll
        for (int kk = 0; kk < 4; kk++) {
            frag a[4], b[4];
#pragma unroll
            for (int i = 0; i < 4; i++)
                a[i] = *(const frag*)&As[wr * 64 + i * 16 + l15][kk * 32 + l4 * 8];
#pragma unroll
            for (int j = 0; j < 4; j++)
                b[j] = *(const frag*)&Ws[((kk * 4 + l4) * 128 + wc * 64 + j * 16 + l15) * 8];
#pragma unroll
            for (int i = 0; i < 4; i++)
#pragma unroll
                for (int j = 0; j < 4; j++)
                    acc[i][j] = __builtin_amdgcn_mfma_f32_16x16x32_bf16(a[i], b[j], acc[i][j], 0, 0, 0);
        }
    }

    // epilogue: C/D layout col = lane&15, row = (lane>>4)*4 + reg  [verified]
#pragma unroll
    for (int j = 0; j < 4; j++) {
        int col = wc * 64 + j * 16 + l15;
        float bv = bias[col];
#pragma unroll
        for (int i = 0; i < 4; i++) {
#pragma unroll
            for (int r = 0; r < 4; r++) {
                int node = nb + wr * 64 + i * 16 + l4 * 4 + r;
                if (node >= NN) continue;
                float v = acc[i][j][r] + bv;
                if (relu) {
                    v = fmaxf(v, 0.f);
                    outH[(size_t)node * 128 + col] = f2bf(v);
                } else {
                    outF[(size_t)node * 128 + col] = v;
                }
            }
        }
    }
}

extern "C" void kernel_launch(void* const* d_in, const int* in_sizes, int n_in,
                              void* d_out, int out_size, void* d_ws, size_t ws_size,
                              hipStream_t stream) {
    const float* x    = (const float*)d_in[0];
    const void* edges = d_in[1];
    const float* Wl1  = (const float*)d_in[2];
    const float* Wr1  = (const float*)d_in[3];
    const float* b1   = (const float*)d_in[4];
    const float* Wl2  = (const float*)d_in[5];
    const float* Wr2  = (const float*)d_in[6];
    const float* b2   = (const float*)d_in[7];
    float* out = (float*)d_out;

    char* ws = (char*)d_ws;
    int* cnt     = (int*)(ws + OFF_CNT);
    int* offsets = (int*)(ws + OFF_OFFS);
    int* cursor  = (int*)(ws + OFF_CUR);
    int* tail    = (int*)(ws + OFF_TAIL);
    int* flag    = (int*)(ws + OFF_TAIL + 64);
    int* csr     = (int*)(ws + OFF_CSR);
    u16* Wst1    = (u16*)(ws + OFF_WT1);
    u16* Wst2    = (u16*)(ws + OFF_WT2);
    u16* xb      = (u16*)(ws + OFF_XB);    // also becomes hb after lin1 (in-place)
    u16* aggb    = (u16*)(ws + OFF_AGGB);

    hipMemsetAsync(cnt, 0, NN * sizeof(int), stream);
    hipMemsetAsync(cursor, 0, NN * sizeof(int), stream);
    hipMemsetAsync(tail, 0, 128, stream);

    detect_kernel<<<1, 1, 0, stream>>>(edges, flag);
    count_kernel<<<(NE + 255) / 256, 256, 0, stream>>>(edges, flag, cnt);
    alloc_kernel<<<(NN + 255) / 256, 256, 0, stream>>>(cnt, offsets, tail);
    fill_kernel<<<(NE + 255) / 256, 256, 0, stream>>>(edges, flag, offsets, cursor, csr);

    wtprep_kernel<<<128, 256, 0, stream>>>(Wl1, Wr1, Wst1);
    wtprep_kernel<<<128, 256, 0, stream>>>(Wl2, Wr2, Wst2);
    cvt_kernel<<<6250, 256, 0, stream>>>(x, xb);

    int lgrid = (NN + 127) / 128;  // 782

    // layer 1: agg1 = mean-gather(xb); h = relu(lin(agg1, xb)) -> bf16, in-place into xb
    agg_kernel<<<NN / 4, 256, 0, stream>>>(xb, csr, offsets, cnt, aggb);
    lin_kernel<<<lgrid, 256, 0, stream>>>(aggb, xb, Wst1, b1, nullptr, xb, 1);

    // layer 2: agg2 = mean-gather(hb); out = lin(agg2, hb) -> f32 d_out
    agg_kernel<<<NN / 4, 256, 0, stream>>>(xb, csr, offsets, cnt, aggb);
    lin_kernel<<<lgrid, 256, 0, stream>>>(aggb, xb, Wst2, b2, out, nullptr, 0);
}

// Round 4
// 396.879 us; speedup vs baseline: 4.9367x; 1.0970x over previous
//
#include <hip/hip_runtime.h>
#include <hip/hip_bf16.h>

#define NN 100000
#define NE 1600000
#define NPART 8
#define PSZ 12500   // NN / NPART
#define NCHUNK 128  // chunks per partition; grid = NPART*NCHUNK = 1024

typedef unsigned short u16;
typedef unsigned int u32;
using frag  = __attribute__((ext_vector_type(8))) short;   // 8 bf16 = 4 VGPR
using f32x4 = __attribute__((ext_vector_type(4))) float;   // MFMA C/D

// ---------------- workspace layout (byte offsets) ----------------
#define OFF_CNT   (0)
#define OFF_OFFS  (512u << 10)
#define OFF_CUR   (1u << 20)
#define OFF_TAIL  (1536u << 10)
#define OFF_CSR   (2u << 20)
#define OFF_WT1   (8704u << 10)
#define OFF_WT2   ((8704u << 10) + 65536u)
#define OFF_XB    (9u << 20)
#define OFF_AGGB  (35037184u)   // OFF_XB + 25,600,000

// round-to-nearest-even f32 -> bf16 bits
__device__ __forceinline__ u16 f2bf(float f) {
    u32 u = __float_as_uint(f);
    u32 r = u + 0x7fffu + ((u >> 16) & 1u);
    return (u16)(r >> 16);
}

__global__ void detect_kernel(const void* edges, int* flag) {
    if (threadIdx.x == 0 && blockIdx.x == 0) {
        const long long* e = (const long long*)edges;
        int ok = 1;
        for (int i = 0; i < 4; i++) {
            long long v = e[i];
            if (v < 0 || v >= NN) ok = 0;
        }
        *flag = ok;
    }
}

// 8-way dst-range partitioned count: part = bid&7 aligns with round-robin
// blockIdx->XCD mapping, so cnt[lo..hi) atomics stay in ONE XCD's L2.
__global__ __launch_bounds__(256) void count_part_kernel(const void* edges, const int* flag,
                                                         int* cnt) {
    int part = blockIdx.x & (NPART - 1);
    int chunk = blockIdx.x >> 3;
    int lo = part * PSZ;
    int f = *flag;
    if (f) {
        const long long* dstp = (const long long*)edges + NE;
        for (int i = chunk * 256 + threadIdx.x; i < NE; i += 256 * NCHUNK) {
            int d = (int)dstp[i];
            if ((u32)(d - lo) < (u32)PSZ) atomicAdd(&cnt[d], 1);
        }
    } else {
        const int* dstp = (const int*)edges + NE;
        for (int i = chunk * 256 + threadIdx.x; i < NE; i += 256 * NCHUNK) {
            int d = dstp[i];
            if ((u32)(d - lo) < (u32)PSZ) atomicAdd(&cnt[d], 1);
        }
    }
}

__global__ void alloc_kernel(const int* cnt, int* offsets, int* tail) {
    int n = blockIdx.x * blockDim.x + threadIdx.x;
    if (n >= NN) return;
    offsets[n] = atomicAdd(tail, cnt[n]);
}

// 8-way dst-range partitioned fill: csr slice (~800KB) + cursor slice (50KB)
// stay resident in the owning XCD's L2 -> each csr line written back once.
__global__ __launch_bounds__(256) void fill_part_kernel(const void* edges, const int* flag,
                                                        const int* offsets, int* cursor,
                                                        int* csr) {
    int part = blockIdx.x & (NPART - 1);
    int chunk = blockIdx.x >> 3;
    int lo = part * PSZ;
    int f = *flag;
    if (f) {
        const long long* e = (const long long*)edges;
        for (int i = chunk * 256 + threadIdx.x; i < NE; i += 256 * NCHUNK) {
            int d = (int)e[NE + i];
            if ((u32)(d - lo) < (u32)PSZ) {
                int s = (int)e[i];
                int pos = atomicAdd(&cursor[d], 1);
                csr[offsets[d] + pos] = s;
            }
        }
    } else {
        const int* e = (const int*)edges;
        for (int i = chunk * 256 + threadIdx.x; i < NE; i += 256 * NCHUNK) {
            int d = e[NE + i];
            if ((u32)(d - lo) < (u32)PSZ) {
                int s = e[i];
                int pos = atomicAdd(&cursor[d], 1);
                csr[offsets[d] + pos] = s;
            }
        }
    }
}

// Wst[kb*1024 + col*8 + i] = bf16( k<128 ? Wl[col][k] : Wr[col][k-128] ), k = kb*8+i
__global__ void wtprep_kernel(const float* Wl, const float* Wr, u16* Wst) {
    int idx = blockIdx.x * 256 + threadIdx.x;
    if (idx >= 32 * 128 * 8) return;
    int kb = idx >> 10, col = (idx >> 3) & 127, i = idx & 7;
    int k = kb * 8 + i;
    float v = (k < 128) ? Wl[col * 128 + k] : Wr[col * 128 + (k - 128)];
    Wst[idx] = f2bf(v);
}

// f32 x -> bf16 xb, 8 elems/thread
__global__ void cvt_kernel(const float* x, u16* xb) {
    size_t base = ((size_t)blockIdx.x * 256 + threadIdx.x) * 8;
    if (base >= (size_t)NN * 128) return;
    float4 v0 = *(const float4*)(x + base);
    float4 v1 = *(const float4*)(x + base + 4);
    uint4 w;
    w.x = (u32)f2bf(v0.x) | ((u32)f2bf(v0.y) << 16);
    w.y = (u32)f2bf(v0.z) | ((u32)f2bf(v0.w) << 16);
    w.z = (u32)f2bf(v1.x) | ((u32)f2bf(v1.y) << 16);
    w.w = (u32)f2bf(v1.z) | ((u32)f2bf(v1.w) << 16);
    *(uint4*)(xb + base) = w;
}

// One wave per node; lane owns 2 bf16 elems (4B) of the 128-wide row. f32 accumulate.
__global__ __launch_bounds__(256) void agg_kernel(const u16* feat, const int* csr,
                                                  const int* offsets, const int* cnt,
                                                  u16* aggb) {
    int node = blockIdx.x * 4 + (threadIdx.x >> 6);
    int lane = threadIdx.x & 63;
    if (node >= NN) return;
    int beg = offsets[node];
    int deg = cnt[node];
    float ax = 0.f, ay = 0.f;
    int j = 0;
    for (; j + 4 <= deg; j += 4) {
        int s0 = csr[beg + j + 0];
        int s1 = csr[beg + j + 1];
        int s2 = csr[beg + j + 2];
        int s3 = csr[beg + j + 3];
        u32 u0 = *(const u32*)(feat + (size_t)s0 * 128 + lane * 2);
        u32 u1 = *(const u32*)(feat + (size_t)s1 * 128 + lane * 2);
        u32 u2 = *(const u32*)(feat + (size_t)s2 * 128 + lane * 2);
        u32 u3 = *(const u32*)(feat + (size_t)s3 * 128 + lane * 2);
        ax += __uint_as_float(u0 << 16) + __uint_as_float(u1 << 16)
            + __uint_as_float(u2 << 16) + __uint_as_float(u3 << 16);
        ay += __uint_as_float(u0 & 0xffff0000u) + __uint_as_float(u1 & 0xffff0000u)
            + __uint_as_float(u2 & 0xffff0000u) + __uint_as_float(u3 & 0xffff0000u);
    }
    for (; j < deg; j++) {
        int s = csr[beg + j];
        u32 u = *(const u32*)(feat + (size_t)s * 128 + lane * 2);
        ax += __uint_as_float(u << 16);
        ay += __uint_as_float(u & 0xffff0000u);
    }
    float inv = (deg > 0) ? 1.0f / (float)deg : 0.0f;
    u32 packed = (u32)f2bf(ax * inv) | ((u32)f2bf(ay * inv) << 16);
    *(u32*)(aggb + (size_t)node * 128 + lane * 2) = packed;
}

// MFMA GEMM: out[n,o] = sum_k [A||B][n,k] * W[k,o] + bias[o], K=256.
__global__ __launch_bounds__(256) void lin_kernel(const u16* __restrict__ Abuf,
                                                  const u16* __restrict__ Bbuf,
                                                  const u16* __restrict__ Wst,
                                                  const float* __restrict__ bias,
                                                  float* outF, u16* outH, int relu) {
    __shared__ u16 As[128][136];   // +8 pad: rows 4 banks apart
    __shared__ u16 Ws[16384];      // [16 kb][128 col][8 k] bf16, chunk-local

    int tid = threadIdx.x;
    int lane = tid & 63;
    int wid = tid >> 6;
    int wr = wid >> 1, wc = wid & 1;
    int nb = blockIdx.x * 128;
    int l15 = lane & 15, l4 = lane >> 4;

    f32x4 acc[4][4];
#pragma unroll
    for (int i = 0; i < 4; i++)
#pragma unroll
        for (int j = 0; j < 4; j++) acc[i][j] = (f32x4){0.f, 0.f, 0.f, 0.f};

    for (int c = 0; c < 2; c++) {
        const u16* Base = c ? Bbuf : Abuf;
        __syncthreads();

#pragma unroll
        for (int it = 0; it < 8; it++) {
            int idx = it * 256 + tid;
            int row = idx >> 4, c16 = idx & 15;
            float4 v = make_float4(0.f, 0.f, 0.f, 0.f);
            if (nb + row < NN)
                v = *(const float4*)(Base + (size_t)(nb + row) * 128 + c16 * 8);
            *(float4*)&As[row][c16 * 8] = v;
        }
        const u16* wsrc = Wst + c * 16384;
#pragma unroll
        for (int it = 0; it < 8; it++) {
            int idx = it * 256 + tid;
            *(float4*)&Ws[idx * 8] = *(const float4*)(wsrc + idx * 8);
        }
        __syncthreads();

#pragma unroll
        for (int kk = 0; kk < 4; kk++) {
            frag a[4], b[4];
#pragma unroll
            for (int i = 0; i < 4; i++)
                a[i] = *(const frag*)&As[wr * 64 + i * 16 + l15][kk * 32 + l4 * 8];
#pragma unroll
            for (int j = 0; j < 4; j++)
                b[j] = *(const frag*)&Ws[((kk * 4 + l4) * 128 + wc * 64 + j * 16 + l15) * 8];
#pragma unroll
            for (int i = 0; i < 4; i++)
#pragma unroll
                for (int j = 0; j < 4; j++)
                    acc[i][j] = __builtin_amdgcn_mfma_f32_16x16x32_bf16(a[i], b[j], acc[i][j], 0, 0, 0);
        }
    }

    // epilogue: C/D layout col = lane&15, row = (lane>>4)*4 + reg
#pragma unroll
    for (int j = 0; j < 4; j++) {
        int col = wc * 64 + j * 16 + l15;
        float bv = bias[col];
#pragma unroll
        for (int i = 0; i < 4; i++) {
#pragma unroll
            for (int r = 0; r < 4; r++) {
                int node = nb + wr * 64 + i * 16 + l4 * 4 + r;
                if (node >= NN) continue;
                float v = acc[i][j][r] + bv;
                if (relu) {
                    v = fmaxf(v, 0.f);
                    outH[(size_t)node * 128 + col] = f2bf(v);
                } else {
                    outF[(size_t)node * 128 + col] = v;
                }
            }
        }
    }
}

extern "C" void kernel_launch(void* const* d_in, const int* in_sizes, int n_in,
                              void* d_out, int out_size, void* d_ws, size_t ws_size,
                              hipStream_t stream) {
    const float* x    = (const float*)d_in[0];
    const void* edges = d_in[1];
    const float* Wl1  = (const float*)d_in[2];
    const float* Wr1  = (const float*)d_in[3];
    const float* b1   = (const float*)d_in[4];
    const float* Wl2  = (const float*)d_in[5];
    const float* Wr2  = (const float*)d_in[6];
    const float* b2   = (const float*)d_in[7];
    float* out = (float*)d_out;

    char* ws = (char*)d_ws;
    int* cnt     = (int*)(ws + OFF_CNT);
    int* offsets = (int*)(ws + OFF_OFFS);
    int* cursor  = (int*)(ws + OFF_CUR);
    int* tail    = (int*)(ws + OFF_TAIL);
    int* flag    = (int*)(ws + OFF_TAIL + 64);
    int* csr     = (int*)(ws + OFF_CSR);
    u16* Wst1    = (u16*)(ws + OFF_WT1);
    u16* Wst2    = (u16*)(ws + OFF_WT2);
    u16* xb      = (u16*)(ws + OFF_XB);    // becomes hb after lin1 (in-place)
    u16* aggb    = (u16*)(ws + OFF_AGGB);

    hipMemsetAsync(cnt, 0, NN * sizeof(int), stream);
    hipMemsetAsync(cursor, 0, NN * sizeof(int), stream);
    hipMemsetAsync(tail, 0, 128, stream);

    detect_kernel<<<1, 1, 0, stream>>>(edges, flag);
    count_part_kernel<<<NPART * NCHUNK, 256, 0, stream>>>(edges, flag, cnt);
    alloc_kernel<<<(NN + 255) / 256, 256, 0, stream>>>(cnt, offsets, tail);
    fill_part_kernel<<<NPART * NCHUNK, 256, 0, stream>>>(edges, flag, offsets, cursor, csr);

    wtprep_kernel<<<128, 256, 0, stream>>>(Wl1, Wr1, Wst1);
    wtprep_kernel<<<128, 256, 0, stream>>>(Wl2, Wr2, Wst2);
    cvt_kernel<<<6250, 256, 0, stream>>>(x, xb);

    int lgrid = (NN + 127) / 128;  // 782

    // layer 1: agg1 = mean-gather(xb); h = relu(lin(agg1, xb)) -> bf16 in-place into xb
    agg_kernel<<<NN / 4, 256, 0, stream>>>(xb, csr, offsets, cnt, aggb);
    lin_kernel<<<lgrid, 256, 0, stream>>>(aggb, xb, Wst1, b1, nullptr, xb, 1);

    // layer 2: agg2 = mean-gather(hb); out = lin(agg2, hb) -> f32 d_out
    agg_kernel<<<NN / 4, 256, 0, stream>>>(xb, csr, offsets, cnt, aggb);
    lin_kernel<<<lgrid, 256, 0, stream>>>(aggb, xb, Wst2, b2, out, nullptr, 0);
}